// Round 1
// baseline (204.370 us; speedup 1.0000x reference)
//
#include <hip/hip_runtime.h>
#include <hip/hip_bf16.h>

#define B_   2048
#define L_   200
#define DM_  512
#define HID_ 256
#define V_   40000
#define NPAD 40064          // 313 * 128, padded N for B^T
#define LN_EPS 1e-5f

typedef short bf16x8 __attribute__((ext_vector_type(8)));
typedef float f32x4  __attribute__((ext_vector_type(4)));

#define GLOAD_LDS16(g, l)                                                     \
    __builtin_amdgcn_global_load_lds(                                         \
        (const __attribute__((address_space(1))) void*)(g),                   \
        (__attribute__((address_space(3))) void*)(l), 16, 0, 0)

// ---------------------------------------------------------------------------
// Kernel 1: W2 (f32, [256][40000]) -> WT (bf16, [NPAD][256])  (transpose+cvt)
// ---------------------------------------------------------------------------
__global__ __launch_bounds__(256) void transpose_w2(const float* __restrict__ W2,
                                                    __hip_bfloat16* __restrict__ WT) {
    __shared__ float tile[64][65];           // +1 pad: conflict-free transpose
    const int n0 = blockIdx.x * 64;          // column block (N dim)
    const int k0 = blockIdx.y * 64;          // row block (K dim)
    const int tid = threadIdx.x;

    const int c = tid & 63, r4 = tid >> 6;   // read: 4 rows per pass
#pragma unroll
    for (int p = 0; p < 16; ++p) {
        int r = p * 4 + r4;
        int n = n0 + c;
        tile[r][c] = (n < V_) ? W2[(size_t)(k0 + r) * V_ + n] : 0.f;
    }
    __syncthreads();

    // write transposed: WT[n][k], 2 k-values per thread as bf16x2 (4B store)
    const int kl = (tid & 31) * 2, nl4 = tid >> 5;
#pragma unroll
    for (int p = 0; p < 8; ++p) {
        int nl = p * 8 + nl4;
        __hip_bfloat162 h2;
        h2.x = __float2bfloat16(tile[kl][nl]);
        h2.y = __float2bfloat16(tile[kl + 1][nl]);
        *(__hip_bfloat162*)(WT + (size_t)(n0 + nl) * HID_ + k0 + kl) = h2;
    }
}

// ---------------------------------------------------------------------------
// Kernel 2: h = GELU(LN(hidden @ W1 + b1)) -> bf16 [2048][256]
// one block = 8 rows, 256 threads (thread j owns output column j)
// ---------------------------------------------------------------------------
__global__ __launch_bounds__(256) void head_kernel(const float* __restrict__ hidden,
                                                   const float* __restrict__ W1,
                                                   const float* __restrict__ b1,
                                                   const float* __restrict__ gamma,
                                                   const float* __restrict__ beta,
                                                   __hip_bfloat16* __restrict__ hout) {
    __shared__ float hid[8][DM_];
    __shared__ float red[2][8][4];
    const int r0 = blockIdx.x * 8;
    const int tid = threadIdx.x;

    // stage 8 rows of hidden (16 KB), coalesced float4
    {
        const float4* src = (const float4*)(hidden + (size_t)r0 * DM_);
        float4* dst = (float4*)(&hid[0][0]);
        for (int i = tid; i < 8 * DM_ / 4; i += 256) dst[i] = src[i];
    }
    __syncthreads();

    float acc[8] = {0.f, 0.f, 0.f, 0.f, 0.f, 0.f, 0.f, 0.f};
#pragma unroll 4
    for (int k = 0; k < DM_; ++k) {
        float w = W1[(size_t)k * HID_ + tid];
#pragma unroll
        for (int r = 0; r < 8; ++r) acc[r] = fmaf(hid[r][k], w, acc[r]);
    }

    const float b1v = b1[tid], gv = gamma[tid], bev = beta[tid];
    const int lane = tid & 63, wv = tid >> 6;

#pragma unroll
    for (int r = 0; r < 8; ++r) {
        float v = acc[r] + b1v;
        float s = v, q = v * v;
#pragma unroll
        for (int off = 1; off < 64; off <<= 1) {
            s += __shfl_xor(s, off);
            q += __shfl_xor(q, off);
        }
        if (lane == 0) { red[0][r][wv] = s; red[1][r][wv] = q; }
    }
    __syncthreads();

#pragma unroll
    for (int r = 0; r < 8; ++r) {
        float s  = red[0][r][0] + red[0][r][1] + red[0][r][2] + red[0][r][3];
        float q  = red[1][r][0] + red[1][r][1] + red[1][r][2] + red[1][r][3];
        float mu = s * (1.f / HID_);
        float var = q * (1.f / HID_) - mu * mu;
        float v  = acc[r] + b1v;
        float hn = (v - mu) * rsqrtf(var + LN_EPS) * gv + bev;
        float g  = 0.5f * hn * (1.f + erff(hn * 0.70710678118654752f));
        hout[(size_t)(r0 + r) * HID_ + tid] = __float2bfloat16(g);
    }
}

// ---------------------------------------------------------------------------
// Kernel 3: out = (h @ W2 + b2) * learned_scale
// bf16 MFMA 16x16x32. Tile 128x128, BK=64, 4 waves (2x2), 4x4 frags/wave.
// A: h bf16 [2048][256]; B: WT bf16 [NPAD][256] (already transposed).
// LDS tiles [128][64] with XOR-8 k-swizzle (pre-swizzled global source).
// ---------------------------------------------------------------------------
#define BM 128
#define BN 128
#define BK 64

__global__ __launch_bounds__(256) void gemm_kernel(const __hip_bfloat16* __restrict__ hA,
                                                   const __hip_bfloat16* __restrict__ BT,
                                                   const float* __restrict__ b2,
                                                   const float* __restrict__ lsp,
                                                   float* __restrict__ out) {
    __shared__ __hip_bfloat16 As[BM * BK];   // 16 KB, swizzled rows
    __shared__ __hip_bfloat16 Bs[BN * BK];   // 16 KB, swizzled rows

    const int r0 = blockIdx.x * BM;          // row tile (fast dim -> B reuse in L2)
    const int c0 = blockIdx.y * BN;          // col tile
    const int tid = threadIdx.x;
    const int lane = tid & 63;
    const int wv = tid >> 6;
    const int wr = (wv >> 1) * 64;           // wave row origin in tile
    const int wc = (wv & 1) * 64;            // wave col origin in tile
    const float ls = lsp[0];

    f32x4 acc[4][4];
#pragma unroll
    for (int m = 0; m < 4; ++m)
#pragma unroll
        for (int n = 0; n < 4; ++n) acc[m][n] = (f32x4){0.f, 0.f, 0.f, 0.f};

    // staging geometry: 16 chunks of (8 rows x 64 bf16 = 1024B); wave wv owns 4.
    // per-lane source pre-swizzle so LDS stays linear (rule #21):
    const int rsub = lane >> 3;                               // row within 8-row chunk
    const int kswz = (((lane & 7) ^ rsub) << 3);              // swizzled k-element
    const __hip_bfloat16* aBase = hA + (size_t)r0 * HID_;
    const __hip_bfloat16* bBase = BT + (size_t)c0 * HID_;

    for (int kk = 0; kk < HID_; kk += BK) {
#pragma unroll
        for (int i = 0; i < 4; ++i) {
            int ch  = wv * 4 + i;
            int row = ch * 8 + rsub;
            GLOAD_LDS16(aBase + (size_t)row * HID_ + kk + kswz,
                        (char*)As + ch * 1024);
            GLOAD_LDS16(bBase + (size_t)row * HID_ + kk + kswz,
                        (char*)Bs + ch * 1024);
        }
        __syncthreads();

#pragma unroll
        for (int ks = 0; ks < BK / 32; ++ks) {
            const int kb = ks * 32 + ((lane >> 4) << 3);      // fragment k-base
            const int ke = kb ^ ((lane & 7) << 3);            // swizzled read
            bf16x8 af[4], bf[4];
            const int rb = wr + (lane & 15);
            const int cb = wc + (lane & 15);
#pragma unroll
            for (int m = 0; m < 4; ++m)
                af[m] = *(const bf16x8*)(As + (rb + m * 16) * BK + ke);
#pragma unroll
            for (int n = 0; n < 4; ++n)
                bf[n] = *(const bf16x8*)(Bs + (cb + n * 16) * BK + ke);
#pragma unroll
            for (int m = 0; m < 4; ++m)
#pragma unroll
                for (int n = 0; n < 4; ++n)
                    acc[m][n] = __builtin_amdgcn_mfma_f32_16x16x32_bf16(
                        af[m], bf[n], acc[m][n], 0, 0, 0);
        }
        __syncthreads();
    }

    // epilogue: C/D layout col = lane&15, row = (lane>>4)*4 + j
    const int colb = c0 + wc + (lane & 15);
    const int rowb = r0 + wr + ((lane >> 4) << 2);
    float b2v[4];
#pragma unroll
    for (int n = 0; n < 4; ++n) {
        int col = colb + n * 16;
        b2v[n] = (col < V_) ? b2[col] : 0.f;
    }
#pragma unroll
    for (int m = 0; m < 4; ++m) {
        float* orow = out + (size_t)(rowb + m * 16) * V_;
#pragma unroll
        for (int n = 0; n < 4; ++n) {
            int col = colb + n * 16;
            if (col < V_) {
#pragma unroll
                for (int j = 0; j < 4; ++j)
                    orow[(size_t)j * V_ + col] = (acc[m][n][j] + b2v[n]) * ls;
            }
        }
    }
}

// ---------------------------------------------------------------------------
// Kernel 4: history scatter, out[b, loc] += (recency + fw) * mask * hs
// ---------------------------------------------------------------------------
__global__ __launch_bounds__(256) void hist_kernel(const int* __restrict__ loc,
                                                   const int* __restrict__ mask,
                                                   const float* __restrict__ rw,
                                                   const float* __restrict__ fw,
                                                   const float* __restrict__ hs,
                                                   float* __restrict__ out) {
    const int idx = blockIdx.x * 256 + threadIdx.x;
    if (idx >= B_ * L_) return;
    const int b = idx / L_, t = idx - b * L_;
    if (mask[idx] != 0) {
        float recency = expf(-0.1f * (float)(L_ - 1 - t)) * rw[0];
        float val = (recency + fw[0]) * hs[0];
        atomicAdd(out + (size_t)b * V_ + loc[idx], val);
    }
}

// ---------------------------------------------------------------------------
extern "C" void kernel_launch(void* const* d_in, const int* in_sizes, int n_in,
                              void* d_out, int out_size, void* d_ws, size_t ws_size,
                              hipStream_t stream) {
    const float* hidden = (const float*)d_in[0];
    const int*   loc    = (const int*)d_in[1];
    const int*   mask   = (const int*)d_in[2];
    const float* W1     = (const float*)d_in[3];
    const float* b1     = (const float*)d_in[4];
    const float* gamma  = (const float*)d_in[5];
    const float* beta   = (const float*)d_in[6];
    const float* W2     = (const float*)d_in[7];
    const float* b2     = (const float*)d_in[8];
    const float* rw     = (const float*)d_in[9];
    const float* fw     = (const float*)d_in[10];
    const float* hs     = (const float*)d_in[11];
    const float* ls     = (const float*)d_in[12];
    float* out = (float*)d_out;

    // workspace layout
    __hip_bfloat16* WT   = (__hip_bfloat16*)d_ws;                       // NPAD*256*2 = 20,512,768 B
    __hip_bfloat16* hbuf = (__hip_bfloat16*)((char*)d_ws + 20512768);   // 2048*256*2 = 1,048,576 B

    transpose_w2<<<dim3(NPAD / 64, HID_ / 64), 256, 0, stream>>>(W2, WT);
    head_kernel<<<B_ / 8, 256, 0, stream>>>(hidden, W1, b1, gamma, beta, hbuf);
    gemm_kernel<<<dim3(B_ / BM, NPAD / BN), 256, 0, stream>>>(hbuf, WT, b2, ls, out);
    hist_kernel<<<(B_ * L_ + 255) / 256, 256, 0, stream>>>(loc, mask, rw, fw, hs, out);
}

// Round 2
// 198.212 us; speedup vs baseline: 1.0311x; 1.0311x over previous
//
#include <hip/hip_runtime.h>
#include <hip/hip_bf16.h>

#define B_   2048
#define L_   200
#define DM_  512
#define HID_ 256
#define V_   40000
#define NPAD 40064          // 313 * 128, padded N for B^T
#define LN_EPS 1e-5f

typedef short bf16x8 __attribute__((ext_vector_type(8)));
typedef float f32x4  __attribute__((ext_vector_type(4)));

#define GLOAD_LDS16(g, l)                                                     \
    __builtin_amdgcn_global_load_lds(                                         \
        (const __attribute__((address_space(1))) void*)(g),                   \
        (__attribute__((address_space(3))) void*)(l), 16, 0, 0)

// ---------------------------------------------------------------------------
// Kernel 1: W2 (f32, [256][40000]) -> WT (bf16, [NPAD][256])  (transpose+cvt)
// ---------------------------------------------------------------------------
__global__ __launch_bounds__(256) void transpose_w2(const float* __restrict__ W2,
                                                    __hip_bfloat16* __restrict__ WT) {
    __shared__ float tile[64][65];           // +1 pad
    const int n0 = blockIdx.x * 64;          // column block (N dim)
    const int k0 = blockIdx.y * 64;          // row block (K dim)
    const int tid = threadIdx.x;

    const int c = tid & 63, r4 = tid >> 6;   // read: 4 rows per pass, coalesced
#pragma unroll
    for (int p = 0; p < 16; ++p) {
        int r = p * 4 + r4;
        int n = n0 + c;
        tile[r][c] = (n < V_) ? W2[(size_t)(k0 + r) * V_ + n] : 0.f;
    }
    __syncthreads();

    // write: thread -> one n-row, 8 consecutive k's, one 16B bf16x8 store
    const int nl = tid >> 3;                 // 0..31
    const int kb = (tid & 7) * 8;            // 0,8,..,56
#pragma unroll
    for (int p = 0; p < 2; ++p) {
        int n = p * 32 + nl;
        bf16x8 v;
#pragma unroll
        for (int j = 0; j < 8; ++j) {
            __hip_bfloat16 h = __float2bfloat16(tile[kb + j][n]);
            v[j] = *(short*)&h;
        }
        *(bf16x8*)(WT + (size_t)(n0 + n) * HID_ + k0 + kb) = v;
    }
}

// ---------------------------------------------------------------------------
// Kernel 2: h = GELU(LN(hidden @ W1 + b1)) -> bf16 [2048][256]
// 512 threads: col = tid&255, K split in half across tid>>8 for 2x ILP/occup.
// ---------------------------------------------------------------------------
__global__ __launch_bounds__(512) void head_kernel(const float* __restrict__ hidden,
                                                   const float* __restrict__ W1,
                                                   const float* __restrict__ b1,
                                                   const float* __restrict__ gamma,
                                                   const float* __restrict__ beta,
                                                   __hip_bfloat16* __restrict__ hout) {
    __shared__ float hid[8][DM_];
    __shared__ float part[8][HID_];
    __shared__ float red[2][8][4];
    const int r0 = blockIdx.x * 8;
    const int tid = threadIdx.x;
    const int col = tid & 255, half = tid >> 8;

    // stage 8 rows of hidden (16 KB), coalesced float4
    {
        const float4* src = (const float4*)(hidden + (size_t)r0 * DM_);
        float4* dst = (float4*)(&hid[0][0]);
        for (int i = tid; i < 8 * DM_ / 4; i += 512) dst[i] = src[i];
    }
    __syncthreads();

    float acc[8] = {0.f, 0.f, 0.f, 0.f, 0.f, 0.f, 0.f, 0.f};
    const int kbeg = half * (DM_ / 2);
#pragma unroll 8
    for (int k = kbeg; k < kbeg + DM_ / 2; ++k) {
        float w = W1[(size_t)k * HID_ + col];
#pragma unroll
        for (int r = 0; r < 8; ++r) acc[r] = fmaf(hid[r][k], w, acc[r]);
    }

    if (half == 1) {
#pragma unroll
        for (int r = 0; r < 8; ++r) part[r][col] = acc[r];
    }
    __syncthreads();
    if (half == 0) {
        const float b1v = b1[col], gv = gamma[col], bev = beta[col];
        const int lane = col & 63, wv = col >> 6;
        float v[8];
#pragma unroll
        for (int r = 0; r < 8; ++r) {
            v[r] = acc[r] + part[r][col] + b1v;
            float s = v[r], q = v[r] * v[r];
#pragma unroll
            for (int off = 1; off < 64; off <<= 1) {
                s += __shfl_xor(s, off);
                q += __shfl_xor(q, off);
            }
            if (lane == 0) { red[0][r][wv] = s; red[1][r][wv] = q; }
        }
        __syncthreads();
#pragma unroll
        for (int r = 0; r < 8; ++r) {
            float s  = red[0][r][0] + red[0][r][1] + red[0][r][2] + red[0][r][3];
            float q  = red[1][r][0] + red[1][r][1] + red[1][r][2] + red[1][r][3];
            float mu = s * (1.f / HID_);
            float var = q * (1.f / HID_) - mu * mu;
            float hn = (v[r] - mu) * rsqrtf(var + LN_EPS) * gv + bev;
            float g  = 0.5f * hn * (1.f + erff(hn * 0.70710678118654752f));
            hout[(size_t)(r0 + r) * HID_ + col] = __float2bfloat16(g);
        }
    }
}

// ---------------------------------------------------------------------------
// Kernel 3: out = (h @ W2 + b2) * learned_scale
// 128x128 tile, BK=64, double-buffered LDS, prefetch-before-compute.
// MFMA operands SWAPPED (C^T trick): acc j-regs = 4 consecutive out cols
//   -> float4 coalesced epilogue, no LDS restage.
// ---------------------------------------------------------------------------
#define BM 128
#define BN 128
#define BK 64
#define NT (HID_ / BK)       // 4 K-steps

__global__ __launch_bounds__(256, 2) void gemm_kernel(const __hip_bfloat16* __restrict__ hA,
                                                      const __hip_bfloat16* __restrict__ BT,
                                                      const float* __restrict__ b2,
                                                      const float* __restrict__ lsp,
                                                      float* __restrict__ out) {
    __shared__ __hip_bfloat16 As[2][BM * BK];   // 2 x 16 KB
    __shared__ __hip_bfloat16 Bs[2][BN * BK];   // 2 x 16 KB

    const int r0 = blockIdx.x * BM;
    const int c0 = blockIdx.y * BN;
    const int tid = threadIdx.x;
    const int lane = tid & 63;
    const int wv = tid >> 6;
    const int wr = (wv >> 1) * 64;
    const int wc = (wv & 1) * 64;
    const float ls = lsp[0];

    f32x4 acc[4][4];
#pragma unroll
    for (int m = 0; m < 4; ++m)
#pragma unroll
        for (int n = 0; n < 4; ++n) acc[m][n] = (f32x4){0.f, 0.f, 0.f, 0.f};

    // staging: 16 chunks of (8 rows x 64 bf16); pre-swizzled global source
    const int rsub = lane >> 3;
    const int kswz = (((lane & 7) ^ rsub) << 3);
    const __hip_bfloat16* aB = hA + (size_t)r0 * HID_;
    const __hip_bfloat16* bB = BT + (size_t)c0 * HID_;

#define STAGE(buf, kk)                                                        \
    {                                                                         \
        _Pragma("unroll")                                                     \
        for (int i = 0; i < 4; ++i) {                                         \
            int ch  = wv * 4 + i;                                             \
            int row = ch * 8 + rsub;                                          \
            GLOAD_LDS16(aB + (size_t)row * HID_ + (kk) + kswz,                \
                        (char*)As[buf] + ch * 1024);                          \
            GLOAD_LDS16(bB + (size_t)row * HID_ + (kk) + kswz,                \
                        (char*)Bs[buf] + ch * 1024);                          \
        }                                                                     \
    }

    STAGE(0, 0);
    __syncthreads();

#pragma unroll
    for (int t = 0; t < NT; ++t) {
        const int cur = t & 1;
        if (t + 1 < NT) STAGE(cur ^ 1, (t + 1) * BK);   // issue BEFORE compute

#pragma unroll
        for (int ks = 0; ks < BK / 32; ++ks) {
            const int kb = ks * 32 + ((lane >> 4) << 3);
            const int ke = kb ^ ((lane & 7) << 3);      // swizzled read
            bf16x8 af[4], bf[4];
            const int rb = wr + (lane & 15);
            const int cb = wc + (lane & 15);
#pragma unroll
            for (int m = 0; m < 4; ++m)
                af[m] = *(const bf16x8*)(As[cur] + (rb + m * 16) * BK + ke);
#pragma unroll
            for (int n = 0; n < 4; ++n)
                bf[n] = *(const bf16x8*)(Bs[cur] + (cb + n * 16) * BK + ke);
#pragma unroll
            for (int m = 0; m < 4; ++m)
#pragma unroll
                for (int n = 0; n < 4; ++n)
                    acc[m][n] = __builtin_amdgcn_mfma_f32_16x16x32_bf16(
                        bf[n], af[m], acc[m][n], 0, 0, 0);   // SWAPPED -> C^T
        }
        __syncthreads();   // drains STAGE(next) vmcnt after compute: overlap
    }

    // epilogue: D^T layout -> lane holds 4 CONSECUTIVE out cols per frag
    //   out_row = r0 + wr + m*16 + (lane&15)
    //   out_col = c0 + wc + n*16 + (lane>>4)*4 + j
    const int orow = r0 + wr + (lane & 15);
    const int ocol = c0 + wc + ((lane >> 4) << 2);
    float4 b2v[4];
#pragma unroll
    for (int n = 0; n < 4; ++n) {
        int col = ocol + n * 16;
        b2v[n] = (col < V_) ? *(const float4*)(b2 + col)
                            : (float4){0.f, 0.f, 0.f, 0.f};
    }
#pragma unroll
    for (int m = 0; m < 4; ++m) {
        float* orp = out + (size_t)(orow + m * 16) * V_;
#pragma unroll
        for (int n = 0; n < 4; ++n) {
            int col = ocol + n * 16;
            if (col < V_) {
                float4 o;
                o.x = (acc[m][n][0] + b2v[n].x) * ls;
                o.y = (acc[m][n][1] + b2v[n].y) * ls;
                o.z = (acc[m][n][2] + b2v[n].z) * ls;
                o.w = (acc[m][n][3] + b2v[n].w) * ls;
                *(float4*)(orp + col) = o;
            }
        }
    }
#undef STAGE
}

// ---------------------------------------------------------------------------
// Kernel 4: history scatter, out[b, loc] += (recency + fw) * mask * hs
// ---------------------------------------------------------------------------
__global__ __launch_bounds__(256) void hist_kernel(const int* __restrict__ loc,
                                                   const int* __restrict__ mask,
                                                   const float* __restrict__ rw,
                                                   const float* __restrict__ fw,
                                                   const float* __restrict__ hs,
                                                   float* __restrict__ out) {
    const int idx = blockIdx.x * 256 + threadIdx.x;
    if (idx >= B_ * L_) return;
    const int b = idx / L_, t = idx - b * L_;
    if (mask[idx] != 0) {
        float recency = expf(-0.1f * (float)(L_ - 1 - t)) * rw[0];
        float val = (recency + fw[0]) * hs[0];
        atomicAdd(out + (size_t)b * V_ + loc[idx], val);
    }
}

// ---------------------------------------------------------------------------
extern "C" void kernel_launch(void* const* d_in, const int* in_sizes, int n_in,
                              void* d_out, int out_size, void* d_ws, size_t ws_size,
                              hipStream_t stream) {
    const float* hidden = (const float*)d_in[0];
    const int*   loc    = (const int*)d_in[1];
    const int*   mask   = (const int*)d_in[2];
    const float* W1     = (const float*)d_in[3];
    const float* b1     = (const float*)d_in[4];
    const float* gamma  = (const float*)d_in[5];
    const float* beta   = (const float*)d_in[6];
    const float* W2     = (const float*)d_in[7];
    const float* b2     = (const float*)d_in[8];
    const float* rw     = (const float*)d_in[9];
    const float* fw     = (const float*)d_in[10];
    const float* hs     = (const float*)d_in[11];
    const float* ls     = (const float*)d_in[12];
    float* out = (float*)d_out;

    __hip_bfloat16* WT   = (__hip_bfloat16*)d_ws;                       // NPAD*256*2
    __hip_bfloat16* hbuf = (__hip_bfloat16*)((char*)d_ws + 20512768);   // 2048*256*2

    transpose_w2<<<dim3(NPAD / 64, HID_ / 64), 256, 0, stream>>>(W2, WT);
    head_kernel<<<B_ / 8, 512, 0, stream>>>(hidden, W1, b1, gamma, beta, hbuf);
    gemm_kernel<<<dim3(B_ / BM, NPAD / BN), 256, 0, stream>>>(hbuf, WT, b2, ls, out);
    hist_kernel<<<(B_ * L_ + 255) / 256, 256, 0, stream>>>(loc, mask, rw, fw, hs, out);
}